// Round 5
// baseline (468.390 us; speedup 1.0000x reference)
//
#include <hip/hip_runtime.h>

#define NB 8
#define NF 16384
#define NE 32768
#define DD 128

static constexpr int ME = NB * NE;  // 262144 edges
static constexpr int MF = NB * NF;  // 131072 faces
static constexpr int CAP = 32;      // face bucket capacity (max deg ~ Poisson(4) << 32)

typedef short bf16x8 __attribute__((ext_vector_type(8)));
typedef float f32x4 __attribute__((ext_vector_type(4)));

#define MFMA16(a, b, c) __builtin_amdgcn_mfma_f32_16x16x32_bf16((a), (b), (c), 0, 0, 0)

static __device__ __forceinline__ unsigned short f2bf(float f) {
  union { float f; unsigned u; } v; v.f = f;
  unsigned r = (v.u + 0x7fffu + ((v.u >> 16) & 1u)) >> 16;
  return (unsigned short)r;
}
static __device__ __forceinline__ float bf2f(unsigned short h) {
  union { unsigned u; float f; } v; v.u = ((unsigned)h) << 16;
  return v.f;
}
static __device__ __forceinline__ bf16x8 pack8(float4 a, float4 b) {
  bf16x8 r;
  r[0] = (short)f2bf(a.x); r[1] = (short)f2bf(a.y);
  r[2] = (short)f2bf(a.z); r[3] = (short)f2bf(a.w);
  r[4] = (short)f2bf(b.x); r[5] = (short)f2bf(b.y);
  r[6] = (short)f2bf(b.z); r[7] = (short)f2bf(b.w);
  return r;
}

// A/B fragment: elements j0..3 at k=kb..kb+3, j4..7 at k=kb+16..kb+19
static __device__ __forceinline__ bf16x8 ld_ab(const unsigned short* p) {
  union { unsigned long long q[2]; bf16x8 v; } u;
  u.q[0] = *(const unsigned long long*)(p);
  u.q[1] = *(const unsigned long long*)(p + 16);
  return u.v;
}

static __device__ __forceinline__ float gelu_exact(float x) {
  return 0.5f * x * (1.0f + erff(x * 0.70710678118654752f));
}
static __device__ __forceinline__ float sigmoidf_(float x) {
  return 1.0f / (1.0f + expf(-x));
}

// Pack fp32 weight (K,N) row-major into bf16 MFMA B-fragment order:
// Wf[((nt*KS + ks)*64 + lane)*8 + j], col = nt*16 + (lane&15),
// k = ks*32 + 16*(j>>2) + 4*(lane>>4) + (j&3)   (same k-map as ld_ab)
__global__ void k_pack(const float* __restrict__ W, unsigned short* __restrict__ Wf,
                       int K, int N) {
  int idx = blockIdx.x * 256 + threadIdx.x;
  if (idx >= K * N) return;
  int j = idx & 7;
  int lane = (idx >> 3) & 63;
  int rest = idx >> 9;
  int KS = K >> 5;
  int ks = rest % KS;
  int nt = rest / KS;
  int col = nt * 16 + (lane & 15);
  int kk = ks * 32 + ((j >> 2) << 4) + ((lane >> 4) << 2) + (j & 3);
  Wf[idx] = f2bf(W[kk * N + col]);
}

// ---- bucket fill: face -> list of incident valid edge ids (stored in out's F region) ----
__global__ void k_fill(const int* __restrict__ e2f, const int* __restrict__ emask,
                       int* __restrict__ cntI, int* __restrict__ outInt) {
  const int eg = blockIdx.x * 256 + threadIdx.x;
  if (eg >= ME) return;
  const int r1 = e2f[2 * eg], r2 = e2f[2 * eg + 1];
  if (!(emask[eg] != 0 && r1 >= 0 && r2 >= 0)) return;
  const int b = eg >> 15;
  const int f1 = r1 > NF - 1 ? NF - 1 : r1;
  const int f2 = r2 > NF - 1 ? NF - 1 : r2;
  const int i1 = b * NF + f1, i2 = b * NF + f2;
  const int p1 = atomicAdd(cntI + i1, 1);
  if (p1 < CAP) outInt[(size_t)i1 * DD + p1] = eg;
  const int p2 = atomicAdd(cntI + i2, 1);
  if (p2 < CAP) outInt[(size_t)i2 * DD + p2] = eg;
}

// ---------------- Edge kernel: 64 edges/block, 8 waves, 2 blocks/CU, NO atomics ----------------
// LDS pool (69376 B):
//   Xe  u16 [64] pitch 136  @0       (17408)  E bf16; live through GEMM3 ks<4
//   Xf  u16 [64] pitch 264  @17408   (33792)  F1|F2; GEMM1 only
//   H   u16 [64] pitch 260  @17408            hidden (aliases Xf)
//   M   f32 [64] pitch 132  @17408            msg fp32 -> u fp32 (aliases H)
//   Mb  u16 [64] pitch 132  @51200   (16896)  msg bf16 for GEMM3 A
//   G   u16 [64] pitch 132  @51200            gate bf16 (aliases Mb)
//   aux @68096: f1s[64] f2s[64] validf[64] mu[64] rs[64]
__global__ __launch_bounds__(512, 4) void k_edge(
    const float* __restrict__ Efeat, const float* __restrict__ Ffeat,
    const int* __restrict__ e2f, const int* __restrict__ emask,
    const unsigned short* __restrict__ W1f, const float* __restrict__ b1,
    const unsigned short* __restrict__ W2f, const float* __restrict__ b2,
    const unsigned short* __restrict__ Wgf, const float* __restrict__ bg,
    const float* __restrict__ ge, const float* __restrict__ be,
    float* __restrict__ out) {
  __shared__ __align__(16) unsigned char pool[69376];
  unsigned short* Xe = (unsigned short*)pool;             // pitch 136
  unsigned short* Xf = (unsigned short*)(pool + 17408);   // pitch 264
  unsigned short* H  = (unsigned short*)(pool + 17408);   // pitch 260
  float*          M  = (float*)(pool + 17408);            // pitch 132
  unsigned short* Mb = (unsigned short*)(pool + 51200);   // pitch 132
  unsigned short* G  = (unsigned short*)(pool + 51200);   // pitch 132
  int*   f1s    = (int*)(pool + 68096);
  int*   f2s    = (int*)(pool + 68352);
  float* validf = (float*)(pool + 68608);
  float* mu     = (float*)(pool + 68864);
  float* rs     = (float*)(pool + 69120);

  const int t = threadIdx.x;
  const int lane = t & 63;
  const int w = t >> 6;   // 0..7
  const int l15 = lane & 15;
  const int l4 = lane >> 4;
  const int eg0 = blockIdx.x * 64;

  if (t < 64) {
    const int eg = eg0 + t;
    const int b = eg >> 15;  // / NE
    const int r1 = e2f[2 * eg], r2 = e2f[2 * eg + 1];
    const bool v = (emask[eg] != 0) && (r1 >= 0) && (r2 >= 0);
    int f1 = r1 < 0 ? 0 : (r1 > NF - 1 ? NF - 1 : r1);
    int f2 = r2 < 0 ? 0 : (r2 > NF - 1 ? NF - 1 : r2);
    f1s[t] = b * NF + f1;
    f2s[t] = b * NF + f2;
    validf[t] = v ? 1.0f : 0.0f;
  }
  __syncthreads();

  // ---- staging: 16B chunks, coalesced global, b128 LDS stores ----
  for (int k = 0; k < 2; ++k) {  // E rows (block-contiguous in global)
    const int c = k * 512 + t, row = c >> 4, j = c & 15;
    const float* s = Efeat + (size_t)(eg0 + row) * DD + j * 8;
    *(bf16x8*)(Xe + row * 136 + j * 8) =
        pack8(*(const float4*)s, *(const float4*)(s + 4));
  }
  for (int k = 0; k < 2; ++k) {  // F1 gathered rows
    const int c = k * 512 + t, row = c >> 4, j = c & 15;
    const float* s1 = Ffeat + (size_t)f1s[row] * DD + j * 8;
    *(bf16x8*)(Xf + row * 264 + j * 8) =
        pack8(*(const float4*)s1, *(const float4*)(s1 + 4));
  }
  for (int k = 0; k < 2; ++k) {  // F2 gathered rows
    const int c = k * 512 + t, row = c >> 4, j = c & 15;
    const float* s2 = Ffeat + (size_t)f2s[row] * DD + j * 8;
    *(bf16x8*)(Xf + row * 264 + 128 + j * 8) =
        pack8(*(const float4*)s2, *(const float4*)(s2 + 4));
  }
  __syncthreads();

  // ---- GEMM1: (64x384)@(384x256), wave w -> cols [32w, 32w+32) ----
  {
    f32x4 acc[4][2] = {};
    for (int ks = 0; ks < 12; ++ks) {
      bf16x8 a[4];
      if (ks < 4) {
        const int kb = ks * 32 + (l4 << 2);
        for (int r = 0; r < 4; ++r) a[r] = ld_ab(Xe + (r * 16 + l15) * 136 + kb);
      } else {
        const int kb = (ks - 4) * 32 + (l4 << 2);
        for (int r = 0; r < 4; ++r) a[r] = ld_ab(Xf + (r * 16 + l15) * 264 + kb);
      }
      for (int n = 0; n < 2; ++n) {
        const int nt = (w << 1) + n;
        bf16x8 bfr = *(const bf16x8*)(W1f + (((nt * 12 + ks) << 6) + lane) * 8);
        for (int r = 0; r < 4; ++r) acc[r][n] = MFMA16(a[r], bfr, acc[r][n]);
      }
    }
    __syncthreads();  // Xf fully read; H may overwrite it
    for (int n = 0; n < 2; ++n) {
      const int col = (w << 5) + (n << 4) + l15;
      const float bias = b1[col];
      for (int r = 0; r < 4; ++r)
        for (int ri = 0; ri < 4; ++ri) {
          const int rw = r * 16 + (l4 << 2) + ri;
          H[rw * 260 + col] = f2bf(gelu_exact(acc[r][n][ri] + bias));
        }
    }
  }
  __syncthreads();

  // ---- GEMM2: (64x256)@(256x128), wave w -> cols [16w, 16w+16) ----
  {
    f32x4 acc2[4] = {};
    for (int ks = 0; ks < 8; ++ks) {
      const int kb = ks * 32 + (l4 << 2);
      bf16x8 a[4];
      for (int r = 0; r < 4; ++r) a[r] = ld_ab(H + (r * 16 + l15) * 260 + kb);
      bf16x8 bfr = *(const bf16x8*)(W2f + (((w * 8 + ks) << 6) + lane) * 8);
      for (int r = 0; r < 4; ++r) acc2[r] = MFMA16(a[r], bfr, acc2[r]);
    }
    __syncthreads();  // H fully read; M may overwrite it
    const int col = (w << 4) + l15;
    const float bias = b2[col];
    for (int r = 0; r < 4; ++r)
      for (int ri = 0; ri < 4; ++ri) {
        const int rw = r * 16 + (l4 << 2) + ri;
        const float mv = (acc2[r][ri] + bias) * validf[rw];
        M[rw * 132 + col] = mv;
        Mb[rw * 132 + col] = f2bf(mv);
      }
  }
  __syncthreads();

  // ---- GEMM3 (gate): [E | msg](64x256)@(256x128), wave w -> cols [16w,16w+16) ----
  {
    f32x4 acc3[4] = {};
    for (int ks = 0; ks < 8; ++ks) {
      bf16x8 a[4];
      if (ks < 4) {
        const int kb = ks * 32 + (l4 << 2);
        for (int r = 0; r < 4; ++r) a[r] = ld_ab(Xe + (r * 16 + l15) * 136 + kb);
      } else {
        const int kb = (ks - 4) * 32 + (l4 << 2);
        for (int r = 0; r < 4; ++r) a[r] = ld_ab(Mb + (r * 16 + l15) * 132 + kb);
      }
      bf16x8 bfr = *(const bf16x8*)(Wgf + (((w * 8 + ks) << 6) + lane) * 8);
      for (int r = 0; r < 4; ++r) acc3[r] = MFMA16(a[r], bfr, acc3[r]);
    }
    __syncthreads();  // Mb fully read; G may overwrite it
    const int col = (w << 4) + l15;
    const float bias = bg[col];
    for (int r = 0; r < 4; ++r)
      for (int ri = 0; ri < 4; ++ri) {
        const int rw = r * 16 + (l4 << 2) + ri;
        G[rw * 132 + col] = f2bf(sigmoidf_(acc3[r][ri] + bias));
      }
  }
  __syncthreads();

  // ---- u = E + gate*msg (coalesced Efeat read; in place into M) ----
  const int colc = t & 127;
  const int rb = t >> 7;  // wave-uniform, 0..3
  const float gec = ge[colc], bec = be[colc];
  for (int i = 0; i < 16; ++i) {
    const int row = 4 * i + rb;
    const float ev = Efeat[(size_t)(eg0 + row) * DD + colc];
    const float gv = bf2f(G[row * 132 + colc]);
    const float mv = M[row * 132 + colc];
    M[row * 132 + colc] = ev + gv * mv;
  }
  __syncthreads();

  {  // ---- LN stats: 8 threads/row ----
    const int rw = t >> 3, q = t & 7;
    const float* ur = M + rw * 132 + q * 16;
    float s = 0.f, s2 = 0.f;
    for (int j = 0; j < 4; ++j) {
      float4 v = *(const float4*)(ur + 4 * j);
      s += v.x + v.y + v.z + v.w;
      s2 += v.x * v.x + v.y * v.y + v.z * v.z + v.w * v.w;
    }
    s += __shfl_xor(s, 1); s2 += __shfl_xor(s2, 1);
    s += __shfl_xor(s, 2); s2 += __shfl_xor(s2, 2);
    s += __shfl_xor(s, 4); s2 += __shfl_xor(s2, 4);
    if (q == 0) {
      const float mean = s * 0.0078125f;
      const float var = s2 * 0.0078125f - mean * mean;
      mu[rw] = mean;
      rs[rw] = rsqrtf(var + 1e-5f);
    }
  }
  __syncthreads();

  // ---- epilogue: coalesced E_new store (no atomics) ----
  float* eob = out + (size_t)MF * DD;
  for (int i = 0; i < 16; ++i) {
    const int row = 4 * i + rb;  // wave-uniform
    const float o = (M[row * 132 + colc] - mu[row]) * rs[row] * gec + bec;
    eob[(size_t)(eg0 + row) * DD + colc] = o;
  }
}

// ---------------- Face kernel: 64 faces/block, 8 waves, 2 blocks/CU ----------------
// LDS pool (68608 B):
//   X   u16 [64] pitch 264 @0      (33792)  [F | msg] bf16
//   G   u16 [64] pitch 132 @0               gate bf16 (aliases X)
//   lid int [64][32]       @33792  (8192)   edge id lists (staging only; aliases H)
//   H   u16 [64] pitch 132 @33792  (16896)  hidden bf16
//   U   f32 [64] pitch 132 @33792  (33792)  update fp32 -> u fp32 (aliases H)
//   aux @67584: fmv[64] cntf[64] mu[64] rs[64]
__global__ __launch_bounds__(512, 4) void k_face(
    const float* __restrict__ Ffeat, const int* __restrict__ fmask,
    const unsigned short* __restrict__ W1f, const float* __restrict__ b1,
    const unsigned short* __restrict__ W2f, const float* __restrict__ b2,
    const unsigned short* __restrict__ Wgf, const float* __restrict__ bg,
    const float* __restrict__ gf, const float* __restrict__ bef,
    float* __restrict__ out, const int* __restrict__ cntI) {
  __shared__ __align__(16) unsigned char pool[68608];
  unsigned short* X = (unsigned short*)pool;              // pitch 264
  unsigned short* G = (unsigned short*)pool;              // pitch 132
  int*          lid = (int*)(pool + 33792);               // [64][32]
  unsigned short* H = (unsigned short*)(pool + 33792);    // pitch 132
  float*          U = (float*)(pool + 33792);             // pitch 132
  float* fmv  = (float*)(pool + 67584);
  float* cntf = (float*)(pool + 67840);
  float* mu   = (float*)(pool + 68096);
  float* rs   = (float*)(pool + 68352);

  const int t = threadIdx.x;
  const int lane = t & 63;
  const int w = t >> 6;
  const int l15 = lane & 15;
  const int l4 = lane >> 4;
  const int fg0 = blockIdx.x * 64;
  const int* outInt = (const int*)out;
  const float* Enew = out + (size_t)MF * DD;

  if (t < 64) {
    fmv[t] = fmask[fg0 + t] ? 1.0f : 0.0f;
    cntf[t] = (float)cntI[fg0 + t];
  }
  // stage id lists: 64 faces x 32 slots
  for (int k = 0; k < 4; ++k) {
    const int idx = k * 512 + t, row = idx >> 5, p = idx & 31;
    lid[idx] = outInt[(size_t)(fg0 + row) * DD + p];
  }
  // stage F half of X
  for (int k = 0; k < 2; ++k) {
    const int c = k * 512 + t, row = c >> 4, j = c & 15;
    const float* sf = Ffeat + (size_t)(fg0 + row) * DD + j * 8;
    *(bf16x8*)(X + row * 264 + j * 8) =
        pack8(*(const float4*)sf, *(const float4*)(sf + 4));
  }
  __syncthreads();

  // ---- gather msg: sum E_new rows over incident edges, /(cnt+eps) ----
  const int colc = t & 127;
  const int rb = t >> 7;  // 0..3, wave-uniform
  for (int i = 0; i < 16; ++i) {
    const int row = 4 * i + rb;
    const int c = (int)cntf[row];
    const int cl = c < CAP ? c : CAP;
    float s = 0.f;
    for (int p = 0; p < cl; ++p)
      s += Enew[(size_t)lid[row * 32 + p] * DD + colc];
    const float msg = s / ((float)c + 1e-8f);
    X[row * 264 + 128 + colc] = f2bf(msg);
  }
  __syncthreads();  // lid dead after this; H may overwrite

  // ---- GEMM ef1: (64x256)@(256x128) -> GELU -> H, wave w -> cols [16w,16w+16) ----
  {
    f32x4 acc[4] = {};
    for (int ks = 0; ks < 8; ++ks) {
      const int kb = ks * 32 + (l4 << 2);
      bf16x8 a[4];
      for (int r = 0; r < 4; ++r) a[r] = ld_ab(X + (r * 16 + l15) * 264 + kb);
      bf16x8 bfr = *(const bf16x8*)(W1f + (((w * 8 + ks) << 6) + lane) * 8);
      for (int r = 0; r < 4; ++r) acc[r] = MFMA16(a[r], bfr, acc[r]);
    }
    const int col = (w << 4) + l15;
    const float bias = b1[col];
    for (int r = 0; r < 4; ++r)
      for (int ri = 0; ri < 4; ++ri) {
        const int rw = r * 16 + (l4 << 2) + ri;
        H[rw * 132 + col] = f2bf(gelu_exact(acc[r][ri] + bias));
      }
  }
  __syncthreads();

  // ---- GEMM ef2: (64x128)@(128x128) -> U fp32 ----
  {
    f32x4 acc2[4] = {};
    for (int ks = 0; ks < 4; ++ks) {
      const int kb = ks * 32 + (l4 << 2);
      bf16x8 a[4];
      for (int r = 0; r < 4; ++r) a[r] = ld_ab(H + (r * 16 + l15) * 132 + kb);
      bf16x8 bfr = *(const bf16x8*)(W2f + (((w * 4 + ks) << 6) + lane) * 8);
      for (int r = 0; r < 4; ++r) acc2[r] = MFMA16(a[r], bfr, acc2[r]);
    }
    __syncthreads();  // H fully read; U may overwrite it
    const int col = (w << 4) + l15;
    const float bias = b2[col];
    for (int r = 0; r < 4; ++r)
      for (int ri = 0; ri < 4; ++ri) {
        const int rw = r * 16 + (l4 << 2) + ri;
        U[rw * 132 + col] = acc2[r][ri] + bias;
      }
  }
  __syncthreads();

  // ---- GEMM gf: [F | update](64x256)@(256x128) ----
  {
    f32x4 acc3[4] = {};
    for (int ks = 0; ks < 8; ++ks) {
      bf16x8 a[4];
      if (ks < 4) {
        const int kb = ks * 32 + (l4 << 2);
        for (int r = 0; r < 4; ++r) a[r] = ld_ab(X + (r * 16 + l15) * 264 + kb);
      } else {
        const int kb = (ks - 4) * 32 + (l4 << 2);
        for (int r = 0; r < 4; ++r) {
          const float* p = U + (r * 16 + l15) * 132 + kb;
          union { unsigned short us[8]; bf16x8 v; } u;
          for (int j = 0; j < 4; ++j) { u.us[j] = f2bf(p[j]); u.us[4 + j] = f2bf(p[16 + j]); }
          a[r] = u.v;
        }
      }
      bf16x8 bfr = *(const bf16x8*)(Wgf + (((w * 8 + ks) << 6) + lane) * 8);
      for (int r = 0; r < 4; ++r) acc3[r] = MFMA16(a[r], bfr, acc3[r]);
    }
    __syncthreads();  // X fully read; G may overwrite it
    const int col = (w << 4) + l15;
    const float bias = bg[col];
    for (int r = 0; r < 4; ++r)
      for (int ri = 0; ri < 4; ++ri) {
        const int rw = r * 16 + (l4 << 2) + ri;
        G[rw * 132 + col] = f2bf(sigmoidf_(acc3[r][ri] + bias));
      }
  }
  __syncthreads();

  // ---- u = F + gate*update*mask (coalesced) ----
  const float gfc = gf[colc], bfc = bef[colc];
  for (int i = 0; i < 16; ++i) {
    const int row = 4 * i + rb;
    const float fv = Ffeat[(size_t)(fg0 + row) * DD + colc];
    const float gv = bf2f(G[row * 132 + colc]);
    const float uv = U[row * 132 + colc];
    U[row * 132 + colc] = fv + gv * uv * fmv[row];
  }
  __syncthreads();

  {  // ---- LN stats: 8 threads/row ----
    const int rw = t >> 3, q = t & 7;
    const float* ur = U + rw * 132 + q * 16;
    float s = 0.f, s2 = 0.f;
    for (int j = 0; j < 4; ++j) {
      float4 v = *(const float4*)(ur + 4 * j);
      s += v.x + v.y + v.z + v.w;
      s2 += v.x * v.x + v.y * v.y + v.z * v.z + v.w * v.w;
    }
    s += __shfl_xor(s, 1); s2 += __shfl_xor(s2, 1);
    s += __shfl_xor(s, 2); s2 += __shfl_xor(s2, 2);
    s += __shfl_xor(s, 4); s2 += __shfl_xor(s2, 4);
    if (q == 0) {
      const float mean = s * 0.0078125f;
      const float var = s2 * 0.0078125f - mean * mean;
      mu[rw] = mean;
      rs[rw] = rsqrtf(var + 1e-5f);
    }
  }
  __syncthreads();

  // ---- epilogue: coalesced F_new store (overwrites id lists) ----
  for (int i = 0; i < 16; ++i) {
    const int row = 4 * i + rb;
    const float o = (U[row * 132 + colc] - mu[row]) * rs[row] * gfc + bfc;
    out[(size_t)(fg0 + row) * DD + colc] = o;
  }
}

extern "C" void kernel_launch(void* const* d_in, const int* in_sizes, int n_in,
                              void* d_out, int out_size, void* d_ws, size_t ws_size,
                              hipStream_t stream) {
  const float* Ffeat = (const float*)d_in[0];
  const float* Efeat = (const float*)d_in[1];
  const int* e2f = (const int*)d_in[2];
  const int* fmask = (const int*)d_in[3];
  const int* emask = (const int*)d_in[4];
  const float* w_fe1 = (const float*)d_in[5];
  const float* b_fe1 = (const float*)d_in[6];
  const float* w_fe2 = (const float*)d_in[7];
  const float* b_fe2 = (const float*)d_in[8];
  const float* w_ge = (const float*)d_in[9];
  const float* b_ge = (const float*)d_in[10];
  const float* g_e = (const float*)d_in[11];
  const float* beta_e = (const float*)d_in[12];
  const float* w_ef1 = (const float*)d_in[13];
  const float* b_ef1 = (const float*)d_in[14];
  const float* w_ef2 = (const float*)d_in[15];
  const float* b_ef2 = (const float*)d_in[16];
  const float* w_gf = (const float*)d_in[17];
  const float* b_gf = (const float*)d_in[18];
  const float* g_f = (const float*)d_in[19];
  const float* beta_f = (const float*)d_in[20];

  float* out = (float*)d_out;
  int* cntI = (int*)d_ws;
  unsigned short* wbase = (unsigned short*)((char*)d_ws + (size_t)MF * sizeof(int));
  unsigned short* W1f = wbase;             // 384*256
  unsigned short* W2f = W1f + 98304;       // 256*128
  unsigned short* Wgf = W2f + 32768;       // 256*128
  unsigned short* Wef1 = Wgf + 32768;      // 256*128
  unsigned short* Wef2 = Wef1 + 32768;     // 128*128
  unsigned short* Wgff = Wef2 + 16384;     // 256*128

  hipMemsetAsync(cntI, 0, (size_t)MF * sizeof(int), stream);

  k_pack<<<(98304 + 255) / 256, 256, 0, stream>>>(w_fe1, W1f, 384, 256);
  k_pack<<<(32768 + 255) / 256, 256, 0, stream>>>(w_fe2, W2f, 256, 128);
  k_pack<<<(32768 + 255) / 256, 256, 0, stream>>>(w_ge, Wgf, 256, 128);
  k_pack<<<(32768 + 255) / 256, 256, 0, stream>>>(w_ef1, Wef1, 256, 128);
  k_pack<<<(16384 + 255) / 256, 256, 0, stream>>>(w_ef2, Wef2, 128, 128);
  k_pack<<<(32768 + 255) / 256, 256, 0, stream>>>(w_gf, Wgff, 256, 128);

  // id lists live in out's F region (dead until k_face overwrites with F_new)
  k_fill<<<ME / 256, 256, 0, stream>>>(e2f, emask, cntI, (int*)out);

  k_edge<<<ME / 64, 512, 0, stream>>>(Efeat, Ffeat, e2f, emask, W1f, b_fe1, W2f, b_fe2,
                                      Wgf, b_ge, g_e, beta_e, out);
  k_face<<<MF / 64, 512, 0, stream>>>(Ffeat, fmask, Wef1, b_ef1, Wef2, b_ef2,
                                      Wgff, b_gf, g_f, beta_f, out, cntI);
}

// Round 7
// 366.376 us; speedup vs baseline: 1.2784x; 1.2784x over previous
//
#include <hip/hip_runtime.h>

#define NB 8
#define NF 16384
#define NE 32768
#define DD 128

static constexpr int ME = NB * NE;  // 262144 edges
static constexpr int MF = NB * NF;  // 131072 faces
static constexpr int CAP = 32;      // face bucket capacity (max deg ~ Poisson(4) << 32)

typedef short bf16x8 __attribute__((ext_vector_type(8)));
typedef float f32x4 __attribute__((ext_vector_type(4)));

#define MFMA16(a, b, c) __builtin_amdgcn_mfma_f32_16x16x32_bf16((a), (b), (c), 0, 0, 0)

// hardware f32->bf16 RNE (validated end-to-end by round-6 k_face pass)
static __device__ __forceinline__ unsigned short f2bf(float f) {
  __bf16 h = (__bf16)f;
  return __builtin_bit_cast(unsigned short, h);
}
static __device__ __forceinline__ float bf2f(unsigned short h) {
  union { unsigned u; float f; } v; v.u = ((unsigned)h) << 16;
  return v.f;
}
static __device__ __forceinline__ bf16x8 pack8(float4 a, float4 b) {
  bf16x8 r;
  r[0] = (short)f2bf(a.x); r[1] = (short)f2bf(a.y);
  r[2] = (short)f2bf(a.z); r[3] = (short)f2bf(a.w);
  r[4] = (short)f2bf(b.x); r[5] = (short)f2bf(b.y);
  r[6] = (short)f2bf(b.z); r[7] = (short)f2bf(b.w);
  return r;
}

// A/B fragment: elements j0..3 at k=kb..kb+3, j4..7 at k=kb+16..kb+19
static __device__ __forceinline__ bf16x8 ld_ab(const unsigned short* p) {
  union { unsigned long long q[2]; bf16x8 v; } u;
  u.q[0] = *(const unsigned long long*)(p);
  u.q[1] = *(const unsigned long long*)(p + 16);
  return u.v;
}

static __device__ __forceinline__ float gelu_exact(float x) {
  return 0.5f * x * (1.0f + erff(x * 0.70710678118654752f));
}
static __device__ __forceinline__ float sigmoidf_(float x) {
  return 1.0f / (1.0f + expf(-x));
}

// ---- merged prologue: 6 weight packs (blocks 0..959) + bucket fill (960..1983) ----
// pack: Wf[((nt*KS+ks)*64+lane)*8+j], col = nt*16+(lane&15),
//       k = ks*32 + 16*(j>>2) + 4*(lane>>4) + (j&3)  (same k-map as ld_ab)
__global__ void k_prep(const float* __restrict__ w_fe1, const float* __restrict__ w_fe2,
                       const float* __restrict__ w_ge, const float* __restrict__ w_ef1,
                       const float* __restrict__ w_ef2, const float* __restrict__ w_gf,
                       unsigned short* __restrict__ W1f, unsigned short* __restrict__ W2f,
                       unsigned short* __restrict__ Wgf, unsigned short* __restrict__ Wef1,
                       unsigned short* __restrict__ Wef2, unsigned short* __restrict__ Wgff,
                       const int* __restrict__ e2f, const int* __restrict__ emask,
                       int* __restrict__ cntI, int* __restrict__ outInt) {
  const int b = blockIdx.x;
  if (b < 960) {
    const float* W; unsigned short* Wf; int K, N, base;
    if (b < 384)      { W = w_fe1; Wf = W1f;  K = 384; N = 256; base = 0; }
    else if (b < 512) { W = w_fe2; Wf = W2f;  K = 256; N = 128; base = 384; }
    else if (b < 640) { W = w_ge;  Wf = Wgf;  K = 256; N = 128; base = 512; }
    else if (b < 768) { W = w_ef1; Wf = Wef1; K = 256; N = 128; base = 640; }
    else if (b < 832) { W = w_ef2; Wf = Wef2; K = 128; N = 128; base = 768; }
    else              { W = w_gf;  Wf = Wgff; K = 256; N = 128; base = 832; }
    const int idx = (b - base) * 256 + threadIdx.x;
    const int j = idx & 7, lane = (idx >> 3) & 63, rest = idx >> 9;
    const int KS = K >> 5, ks = rest % KS, nt = rest / KS;
    const int col = nt * 16 + (lane & 15);
    const int kk = ks * 32 + ((j >> 2) << 4) + ((lane >> 4) << 2) + (j & 3);
    Wf[idx] = f2bf(W[kk * N + col]);
  } else {
    const int eg = (b - 960) * 256 + threadIdx.x;
    const int r1 = e2f[2 * eg], r2 = e2f[2 * eg + 1];
    if (!(emask[eg] != 0 && r1 >= 0 && r2 >= 0)) return;
    const int bb = eg >> 15;
    const int f1 = r1 > NF - 1 ? NF - 1 : r1;
    const int f2 = r2 > NF - 1 ? NF - 1 : r2;
    const int i1 = bb * NF + f1, i2 = bb * NF + f2;
    const int p1 = atomicAdd(cntI + i1, 1);
    if (p1 < CAP) outInt[(size_t)i1 * DD + p1] = eg;
    const int p2 = atomicAdd(cntI + i2, 1);
    if (p2 < CAP) outInt[(size_t)i2 * DD + p2] = eg;
  }
}

// ---------------- Edge kernel: EXACT round-5 proven body (64 edges/block, 8 waves) ----------------
// LDS pool (69376 B):
//   Xe  u16 [64] pitch 136  @0       (17408)  E bf16; live through GEMM3 ks<4
//   Xf  u16 [64] pitch 264  @17408   (33792)  F1|F2; GEMM1 only
//   H   u16 [64] pitch 260  @17408            hidden (aliases Xf)
//   M   f32 [64] pitch 132  @17408            msg fp32 -> u fp32 (aliases H)
//   Mb  u16 [64] pitch 132  @51200   (16896)  msg bf16 for GEMM3 A
//   G   u16 [64] pitch 132  @51200            gate bf16 (aliases Mb)
//   aux @68096: f1s[64] f2s[64] validf[64] mu[64] rs[64]
__global__ __launch_bounds__(512, 4) void k_edge(
    const float* __restrict__ Efeat, const float* __restrict__ Ffeat,
    const int* __restrict__ e2f, const int* __restrict__ emask,
    const unsigned short* __restrict__ W1f, const float* __restrict__ b1,
    const unsigned short* __restrict__ W2f, const float* __restrict__ b2,
    const unsigned short* __restrict__ Wgf, const float* __restrict__ bg,
    const float* __restrict__ ge, const float* __restrict__ be,
    float* __restrict__ out) {
  __shared__ __align__(16) unsigned char pool[69376];
  unsigned short* Xe = (unsigned short*)pool;             // pitch 136
  unsigned short* Xf = (unsigned short*)(pool + 17408);   // pitch 264
  unsigned short* H  = (unsigned short*)(pool + 17408);   // pitch 260
  float*          M  = (float*)(pool + 17408);            // pitch 132
  unsigned short* Mb = (unsigned short*)(pool + 51200);   // pitch 132
  unsigned short* G  = (unsigned short*)(pool + 51200);   // pitch 132
  int*   f1s    = (int*)(pool + 68096);
  int*   f2s    = (int*)(pool + 68352);
  float* validf = (float*)(pool + 68608);
  float* mu     = (float*)(pool + 68864);
  float* rs     = (float*)(pool + 69120);

  const int t = threadIdx.x;
  const int lane = t & 63;
  const int w = t >> 6;   // 0..7
  const int l15 = lane & 15;
  const int l4 = lane >> 4;
  const int eg0 = blockIdx.x * 64;

  if (t < 64) {
    const int eg = eg0 + t;
    const int b = eg >> 15;  // / NE
    const int r1 = e2f[2 * eg], r2 = e2f[2 * eg + 1];
    const bool v = (emask[eg] != 0) && (r1 >= 0) && (r2 >= 0);
    int f1 = r1 < 0 ? 0 : (r1 > NF - 1 ? NF - 1 : r1);
    int f2 = r2 < 0 ? 0 : (r2 > NF - 1 ? NF - 1 : r2);
    f1s[t] = b * NF + f1;
    f2s[t] = b * NF + f2;
    validf[t] = v ? 1.0f : 0.0f;
  }
  __syncthreads();

  // ---- staging: 16B chunks, coalesced global, b128 LDS stores ----
  for (int k = 0; k < 2; ++k) {  // E rows (block-contiguous in global)
    const int c = k * 512 + t, row = c >> 4, j = c & 15;
    const float* s = Efeat + (size_t)(eg0 + row) * DD + j * 8;
    *(bf16x8*)(Xe + row * 136 + j * 8) =
        pack8(*(const float4*)s, *(const float4*)(s + 4));
  }
  for (int k = 0; k < 2; ++k) {  // F1 gathered rows
    const int c = k * 512 + t, row = c >> 4, j = c & 15;
    const float* s1 = Ffeat + (size_t)f1s[row] * DD + j * 8;
    *(bf16x8*)(Xf + row * 264 + j * 8) =
        pack8(*(const float4*)s1, *(const float4*)(s1 + 4));
  }
  for (int k = 0; k < 2; ++k) {  // F2 gathered rows
    const int c = k * 512 + t, row = c >> 4, j = c & 15;
    const float* s2 = Ffeat + (size_t)f2s[row] * DD + j * 8;
    *(bf16x8*)(Xf + row * 264 + 128 + j * 8) =
        pack8(*(const float4*)s2, *(const float4*)(s2 + 4));
  }
  __syncthreads();

  // ---- GEMM1: (64x384)@(384x256), wave w -> cols [32w, 32w+32) ----
  {
    f32x4 acc[4][2] = {};
    for (int ks = 0; ks < 12; ++ks) {
      bf16x8 a[4];
      if (ks < 4) {
        const int kb = ks * 32 + (l4 << 2);
        for (int r = 0; r < 4; ++r) a[r] = ld_ab(Xe + (r * 16 + l15) * 136 + kb);
      } else {
        const int kb = (ks - 4) * 32 + (l4 << 2);
        for (int r = 0; r < 4; ++r) a[r] = ld_ab(Xf + (r * 16 + l15) * 264 + kb);
      }
      for (int n = 0; n < 2; ++n) {
        const int nt = (w << 1) + n;
        bf16x8 bfr = *(const bf16x8*)(W1f + (((nt * 12 + ks) << 6) + lane) * 8);
        for (int r = 0; r < 4; ++r) acc[r][n] = MFMA16(a[r], bfr, acc[r][n]);
      }
    }
    __syncthreads();  // Xf fully read; H may overwrite it
    for (int n = 0; n < 2; ++n) {
      const int col = (w << 5) + (n << 4) + l15;
      const float bias = b1[col];
      for (int r = 0; r < 4; ++r)
        for (int ri = 0; ri < 4; ++ri) {
          const int rw = r * 16 + (l4 << 2) + ri;
          H[rw * 260 + col] = f2bf(gelu_exact(acc[r][n][ri] + bias));
        }
    }
  }
  __syncthreads();

  // ---- GEMM2: (64x256)@(256x128), wave w -> cols [16w, 16w+16) ----
  {
    f32x4 acc2[4] = {};
    for (int ks = 0; ks < 8; ++ks) {
      const int kb = ks * 32 + (l4 << 2);
      bf16x8 a[4];
      for (int r = 0; r < 4; ++r) a[r] = ld_ab(H + (r * 16 + l15) * 260 + kb);
      bf16x8 bfr = *(const bf16x8*)(W2f + (((w * 8 + ks) << 6) + lane) * 8);
      for (int r = 0; r < 4; ++r) acc2[r] = MFMA16(a[r], bfr, acc2[r]);
    }
    __syncthreads();  // H fully read; M may overwrite it
    const int col = (w << 4) + l15;
    const float bias = b2[col];
    for (int r = 0; r < 4; ++r)
      for (int ri = 0; ri < 4; ++ri) {
        const int rw = r * 16 + (l4 << 2) + ri;
        const float mv = (acc2[r][ri] + bias) * validf[rw];
        M[rw * 132 + col] = mv;
        Mb[rw * 132 + col] = f2bf(mv);
      }
  }
  __syncthreads();

  // ---- GEMM3 (gate): [E | msg](64x256)@(256x128), wave w -> cols [16w,16w+16) ----
  {
    f32x4 acc3[4] = {};
    for (int ks = 0; ks < 8; ++ks) {
      bf16x8 a[4];
      if (ks < 4) {
        const int kb = ks * 32 + (l4 << 2);
        for (int r = 0; r < 4; ++r) a[r] = ld_ab(Xe + (r * 16 + l15) * 136 + kb);
      } else {
        const int kb = (ks - 4) * 32 + (l4 << 2);
        for (int r = 0; r < 4; ++r) a[r] = ld_ab(Mb + (r * 16 + l15) * 132 + kb);
      }
      bf16x8 bfr = *(const bf16x8*)(Wgf + (((w * 8 + ks) << 6) + lane) * 8);
      for (int r = 0; r < 4; ++r) acc3[r] = MFMA16(a[r], bfr, acc3[r]);
    }
    __syncthreads();  // Mb fully read; G may overwrite it
    const int col = (w << 4) + l15;
    const float bias = bg[col];
    for (int r = 0; r < 4; ++r)
      for (int ri = 0; ri < 4; ++ri) {
        const int rw = r * 16 + (l4 << 2) + ri;
        G[rw * 132 + col] = f2bf(sigmoidf_(acc3[r][ri] + bias));
      }
  }
  __syncthreads();

  // ---- u = E + gate*msg (coalesced Efeat read; in place into M) ----
  const int colc = t & 127;
  const int rb = t >> 7;  // wave-uniform, 0..3
  const float gec = ge[colc], bec = be[colc];
  for (int i = 0; i < 16; ++i) {
    const int row = 4 * i + rb;
    const float ev = Efeat[(size_t)(eg0 + row) * DD + colc];
    const float gv = bf2f(G[row * 132 + colc]);
    const float mv = M[row * 132 + colc];
    M[row * 132 + colc] = ev + gv * mv;
  }
  __syncthreads();

  {  // ---- LN stats: 8 threads/row ----
    const int rw = t >> 3, q = t & 7;
    const float* ur = M + rw * 132 + q * 16;
    float s = 0.f, s2 = 0.f;
    for (int j = 0; j < 4; ++j) {
      float4 v = *(const float4*)(ur + 4 * j);
      s += v.x + v.y + v.z + v.w;
      s2 += v.x * v.x + v.y * v.y + v.z * v.z + v.w * v.w;
    }
    s += __shfl_xor(s, 1); s2 += __shfl_xor(s2, 1);
    s += __shfl_xor(s, 2); s2 += __shfl_xor(s2, 2);
    s += __shfl_xor(s, 4); s2 += __shfl_xor(s2, 4);
    if (q == 0) {
      const float mean = s * 0.0078125f;
      const float var = s2 * 0.0078125f - mean * mean;
      mu[rw] = mean;
      rs[rw] = rsqrtf(var + 1e-5f);
    }
  }
  __syncthreads();

  // ---- epilogue: coalesced E_new store (no atomics) ----
  float* eob = out + (size_t)MF * DD;
  for (int i = 0; i < 16; ++i) {
    const int row = 4 * i + rb;  // wave-uniform
    const float o = (M[row * 132 + colc] - mu[row]) * rs[row] * gec + bec;
    eob[(size_t)(eg0 + row) * DD + colc] = o;
  }
}

// ---------------- Face kernel: round-6 proven body (64 faces/block, 8 waves, 3 blocks/CU) ----------------
// LDS pool (51712 B):
//   X  @0     (33792)  [F | msg] bf16, pitch 264; live through final epilogue
//   B  @33792 (17408)  lid[64][32] ints (gather) -> H (pitch 136) -> Ub (pitch 136, gated)
//   aux @51200: cnts[64] fmv[64]
__global__ __launch_bounds__(512, 6) void k_face(
    const float* __restrict__ Ffeat, const int* __restrict__ fmask,
    const unsigned short* __restrict__ W1f, const float* __restrict__ b1,
    const unsigned short* __restrict__ W2f, const float* __restrict__ b2,
    const unsigned short* __restrict__ Wgf, const float* __restrict__ bg,
    const float* __restrict__ gf, const float* __restrict__ bef,
    float* __restrict__ out, const int* __restrict__ cntI) {
  __shared__ __align__(16) unsigned char pool[51712];
  unsigned short* X  = (unsigned short*)pool;             // pitch 264
  int*          lid  = (int*)(pool + 33792);              // [64][32]
  unsigned short* H  = (unsigned short*)(pool + 33792);   // pitch 136
  unsigned short* Ub = (unsigned short*)(pool + 33792);   // pitch 136
  int*   cnts = (int*)(pool + 51200);
  float* fmv  = (float*)(pool + 51456);

  const int t = threadIdx.x;
  const int lane = t & 63;
  const int w = t >> 6;
  const int l15 = lane & 15;
  const int l4 = lane >> 4;
  const int fg0 = blockIdx.x * 64;
  const int* outInt = (const int*)out;
  const float* Enew = out + (size_t)MF * DD;

  if (t < 64) {
    fmv[t] = fmask[fg0 + t] ? 1.0f : 0.0f;
    cnts[t] = cntI[fg0 + t];
  }
  for (int k = 0; k < 4; ++k) {  // stage id lists
    const int idx = k * 512 + t, row = idx >> 5, p = idx & 31;
    lid[idx] = outInt[(size_t)(fg0 + row) * DD + p];
  }
  for (int k = 0; k < 2; ++k) {  // stage F half of X
    const int c = k * 512 + t, row = c >> 4, j = c & 15;
    const float* sf = Ffeat + (size_t)(fg0 + row) * DD + j * 8;
    *(bf16x8*)(X + row * 264 + j * 8) =
        pack8(*(const float4*)sf, *(const float4*)(sf + 4));
  }
  __syncthreads();

  // ---- gather msg: parallel predicated 8-wide prefetch + rare tail ----
  {
    const int colc = t & 127;
    const int rb = t >> 7;  // 0..3
    for (int i = 0; i < 16; ++i) {
      const int row = 4 * i + rb;
      const int c = cnts[row];
      const int cl = c < CAP ? c : CAP;
      const int* lr = lid + row * 32;
      float s = 0.f;
#pragma unroll
      for (int p = 0; p < 8; ++p) {
        const int idx = (p < cl) ? lr[p] : 0;
        const float v = Enew[(size_t)idx * DD + colc];
        s += (p < cl) ? v : 0.f;
      }
      for (int p = 8; p < cl; ++p) s += Enew[(size_t)lr[p] * DD + colc];
      X[row * 264 + 128 + colc] = f2bf(s / ((float)c + 1e-8f));
    }
  }
  __syncthreads();  // msg complete; lid dead (H may overwrite)

  // ---- GEMM ef1: (64x256)@(256x128) -> GELU -> H, wave w -> cols [16w,16w+16) ----
  {
    f32x4 acc[4] = {};
    for (int ks = 0; ks < 8; ++ks) {
      const int kb = ks * 32 + (l4 << 2);
      bf16x8 a[4];
      for (int r = 0; r < 4; ++r) a[r] = ld_ab(X + (r * 16 + l15) * 264 + kb);
      bf16x8 bfr = *(const bf16x8*)(W1f + (((w * 8 + ks) << 6) + lane) * 8);
      for (int r = 0; r < 4; ++r) acc[r] = MFMA16(a[r], bfr, acc[r]);
    }
    const int col = (w << 4) + l15;
    const float bias = b1[col];
    for (int r = 0; r < 4; ++r)
      for (int ri = 0; ri < 4; ++ri) {
        const int rw = r * 16 + (l4 << 2) + ri;
        H[rw * 136 + col] = f2bf(gelu_exact(acc[r][ri] + bias));
      }
  }
  __syncthreads();

  // ---- GEMM ef2: (64x128)@(128x128) -> Ub bf16 (in place over H) ----
  {
    f32x4 acc2[4] = {};
    for (int ks = 0; ks < 4; ++ks) {
      const int kb = ks * 32 + (l4 << 2);
      bf16x8 a[4];
      for (int r = 0; r < 4; ++r) a[r] = ld_ab(H + (r * 16 + l15) * 136 + kb);
      bf16x8 bfr = *(const bf16x8*)(W2f + (((w * 4 + ks) << 6) + lane) * 8);
      for (int r = 0; r < 4; ++r) acc2[r] = MFMA16(a[r], bfr, acc2[r]);
    }
    __syncthreads();  // H fully read; Ub overwrites same cells
    const int col = (w << 4) + l15;
    const float bias = b2[col];
    for (int r = 0; r < 4; ++r)
      for (int ri = 0; ri < 4; ++ri) {
        const int rw = r * 16 + (l4 << 2) + ri;
        Ub[rw * 136 + col] = f2bf(acc2[r][ri] + bias);
      }
  }
  __syncthreads();

  // ---- GEMM gf: [F | update](64x256)@(256x128); then gate-fold into Ub ----
  {
    f32x4 acc3[4] = {};
    for (int ks = 0; ks < 8; ++ks) {
      bf16x8 a[4];
      if (ks < 4) {
        const int kb = ks * 32 + (l4 << 2);
        for (int r = 0; r < 4; ++r) a[r] = ld_ab(X + (r * 16 + l15) * 264 + kb);
      } else {
        const int kb = (ks - 4) * 32 + (l4 << 2);
        for (int r = 0; r < 4; ++r) a[r] = ld_ab(Ub + (r * 16 + l15) * 136 + kb);
      }
      bf16x8 bfr = *(const bf16x8*)(Wgf + (((w * 8 + ks) << 6) + lane) * 8);
      for (int r = 0; r < 4; ++r) acc3[r] = MFMA16(a[r], bfr, acc3[r]);
    }
    __syncthreads();  // Ub fully read; fold rewrites in place (with face mask)
    const int col = (w << 4) + l15;
    const float bias = bg[col];
    for (int r = 0; r < 4; ++r)
      for (int ri = 0; ri < 4; ++ri) {
        const int rw = r * 16 + (l4 << 2) + ri;
        const int off = rw * 136 + col;
        Ub[off] = f2bf(sigmoidf_(acc3[r][ri] + bias) * bf2f(Ub[off]) * fmv[rw]);
      }
  }
  __syncthreads();

  // ---- fused u + LN + store F_new (overwrites id-list region of out) ----
  {
    const int rw = t >> 3, q = t & 7;
    const unsigned short* xf = X + rw * 264 + q * 16;
    const unsigned short* ub = Ub + rw * 136 + q * 16;
    bf16x8 e0 = *(const bf16x8*)(xf), e1 = *(const bf16x8*)(xf + 8);
    bf16x8 m0 = *(const bf16x8*)(ub), m1 = *(const bf16x8*)(ub + 8);
    float u[16];
    float s = 0.f, s2 = 0.f;
    for (int jj = 0; jj < 8; ++jj) {
      const float v0 = bf2f((unsigned short)e0[jj]) + bf2f((unsigned short)m0[jj]);
      const float v1 = bf2f((unsigned short)e1[jj]) + bf2f((unsigned short)m1[jj]);
      u[jj] = v0; u[8 + jj] = v1;
      s += v0 + v1; s2 += v0 * v0 + v1 * v1;
    }
    s += __shfl_xor(s, 1); s2 += __shfl_xor(s2, 1);
    s += __shfl_xor(s, 2); s2 += __shfl_xor(s2, 2);
    s += __shfl_xor(s, 4); s2 += __shfl_xor(s2, 4);
    const float mean = s * 0.0078125f;
    const float var = s2 * 0.0078125f - mean * mean;
    const float rstd = rsqrtf(var + 1e-5f);
    float* fo = out + (size_t)(fg0 + rw) * DD + q * 16;
    const float* gfp = gf + q * 16;
    const float* bfp = bef + q * 16;
    for (int c4 = 0; c4 < 4; ++c4) {
      float4 g4 = ((const float4*)gfp)[c4];
      float4 b4 = ((const float4*)bfp)[c4];
      float4 o4;
      o4.x = (u[c4 * 4 + 0] - mean) * rstd * g4.x + b4.x;
      o4.y = (u[c4 * 4 + 1] - mean) * rstd * g4.y + b4.y;
      o4.z = (u[c4 * 4 + 2] - mean) * rstd * g4.z + b4.z;
      o4.w = (u[c4 * 4 + 3] - mean) * rstd * g4.w + b4.w;
      ((float4*)fo)[c4] = o4;
    }
  }
}

extern "C" void kernel_launch(void* const* d_in, const int* in_sizes, int n_in,
                              void* d_out, int out_size, void* d_ws, size_t ws_size,
                              hipStream_t stream) {
  const float* Ffeat = (const float*)d_in[0];
  const float* Efeat = (const float*)d_in[1];
  const int* e2f = (const int*)d_in[2];
  const int* fmask = (const int*)d_in[3];
  const int* emask = (const int*)d_in[4];
  const float* w_fe1 = (const float*)d_in[5];
  const float* b_fe1 = (const float*)d_in[6];
  const float* w_fe2 = (const float*)d_in[7];
  const float* b_fe2 = (const float*)d_in[8];
  const float* w_ge = (const float*)d_in[9];
  const float* b_ge = (const float*)d_in[10];
  const float* g_e = (const float*)d_in[11];
  const float* beta_e = (const float*)d_in[12];
  const float* w_ef1 = (const float*)d_in[13];
  const float* b_ef1 = (const float*)d_in[14];
  const float* w_ef2 = (const float*)d_in[15];
  const float* b_ef2 = (const float*)d_in[16];
  const float* w_gf = (const float*)d_in[17];
  const float* b_gf = (const float*)d_in[18];
  const float* g_f = (const float*)d_in[19];
  const float* beta_f = (const float*)d_in[20];

  float* out = (float*)d_out;
  int* cntI = (int*)d_ws;
  unsigned short* wbase = (unsigned short*)((char*)d_ws + (size_t)MF * sizeof(int));
  unsigned short* W1f = wbase;             // 384*256
  unsigned short* W2f = W1f + 98304;       // 256*128
  unsigned short* Wgf = W2f + 32768;       // 256*128
  unsigned short* Wef1 = Wgf + 32768;      // 256*128
  unsigned short* Wef2 = Wef1 + 32768;     // 128*128
  unsigned short* Wgff = Wef2 + 16384;     // 256*128

  hipMemsetAsync(cntI, 0, (size_t)MF * sizeof(int), stream);

  // one merged prologue launch: 960 pack blocks + 1024 fill blocks
  k_prep<<<1984, 256, 0, stream>>>(w_fe1, w_fe2, w_ge, w_ef1, w_ef2, w_gf,
                                   W1f, W2f, Wgf, Wef1, Wef2, Wgff,
                                   e2f, emask, cntI, (int*)out);

  k_edge<<<ME / 64, 512, 0, stream>>>(Efeat, Ffeat, e2f, emask, W1f, b_fe1, W2f, b_fe2,
                                      Wgf, b_ge, g_e, beta_e, out);
  k_face<<<MF / 64, 512, 0, stream>>>(Ffeat, fmask, Wef1, b_ef1, Wef2, b_ef2,
                                      Wgff, b_gf, g_f, beta_f, out, cntI);
}

// Round 10
// 358.869 us; speedup vs baseline: 1.3052x; 1.0209x over previous
//
#include <hip/hip_runtime.h>

#define NB 8
#define NF 16384
#define NE 32768
#define DD 128

static constexpr int ME = NB * NE;  // 262144 edges
static constexpr int MF = NB * NF;  // 131072 faces
static constexpr int CAP = 32;      // face bucket capacity (max deg ~ Poisson(4) << 32)

typedef short bf16x8 __attribute__((ext_vector_type(8)));
typedef float f32x4 __attribute__((ext_vector_type(4)));

#define MFMA16(a, b, c) __builtin_amdgcn_mfma_f32_16x16x32_bf16((a), (b), (c), 0, 0, 0)

// hardware f32->bf16 RNE
static __device__ __forceinline__ unsigned short f2bf(float f) {
  __bf16 h = (__bf16)f;
  return __builtin_bit_cast(unsigned short, h);
}
static __device__ __forceinline__ float bf2f(unsigned short h) {
  union { unsigned u; float f; } v; v.u = ((unsigned)h) << 16;
  return v.f;
}
static __device__ __forceinline__ bf16x8 pack8(float4 a, float4 b) {
  bf16x8 r;
  r[0] = (short)f2bf(a.x); r[1] = (short)f2bf(a.y);
  r[2] = (short)f2bf(a.z); r[3] = (short)f2bf(a.w);
  r[4] = (short)f2bf(b.x); r[5] = (short)f2bf(b.y);
  r[6] = (short)f2bf(b.z); r[7] = (short)f2bf(b.w);
  return r;
}

// A/B fragment: elements j0..3 at k=kb..kb+3, j4..7 at k=kb+16..kb+19
static __device__ __forceinline__ bf16x8 ld_ab(const unsigned short* p) {
  union { unsigned long long q[2]; bf16x8 v; } u;
  u.q[0] = *(const unsigned long long*)(p);
  u.q[1] = *(const unsigned long long*)(p + 16);
  return u.v;
}

// tanh-form GELU via hw exp: x/(1+e^{-2y}), 2y = 1.59577x + 0.0713548x^3.
// |err vs exact erf-GELU| <= ~6e-4; downstream error ~2e-4 vs 0.1075 budget.
static __device__ __forceinline__ float gelu_fast(float x) {
  const float z = x * (1.5957691216f + 0.0713548163f * x * x);
  return __fdividef(x, 1.0f + __expf(-z));
}
static __device__ __forceinline__ float sigmoid_fast(float x) {
  return __fdividef(1.0f, 1.0f + __expf(-x));
}

// ---- merged prologue: 6 weight packs (blocks 0..959) + bucket fill (960..1983) ----
__global__ void k_prep(const float* __restrict__ w_fe1, const float* __restrict__ w_fe2,
                       const float* __restrict__ w_ge, const float* __restrict__ w_ef1,
                       const float* __restrict__ w_ef2, const float* __restrict__ w_gf,
                       unsigned short* __restrict__ W1f, unsigned short* __restrict__ W2f,
                       unsigned short* __restrict__ Wgf, unsigned short* __restrict__ Wef1,
                       unsigned short* __restrict__ Wef2, unsigned short* __restrict__ Wgff,
                       const int* __restrict__ e2f, const int* __restrict__ emask,
                       int* __restrict__ cntI, int* __restrict__ outInt) {
  const int b = blockIdx.x;
  if (b < 960) {
    const float* W; unsigned short* Wf; int K, N, base;
    if (b < 384)      { W = w_fe1; Wf = W1f;  K = 384; N = 256; base = 0; }
    else if (b < 512) { W = w_fe2; Wf = W2f;  K = 256; N = 128; base = 384; }
    else if (b < 640) { W = w_ge;  Wf = Wgf;  K = 256; N = 128; base = 512; }
    else if (b < 768) { W = w_ef1; Wf = Wef1; K = 256; N = 128; base = 640; }
    else if (b < 832) { W = w_ef2; Wf = Wef2; K = 128; N = 128; base = 768; }
    else              { W = w_gf;  Wf = Wgff; K = 256; N = 128; base = 832; }
    const int idx = (b - base) * 256 + threadIdx.x;
    const int j = idx & 7, lane = (idx >> 3) & 63, rest = idx >> 9;
    const int KS = K >> 5, ks = rest % KS, nt = rest / KS;
    const int col = nt * 16 + (lane & 15);
    const int kk = ks * 32 + ((j >> 2) << 4) + ((lane >> 4) << 2) + (j & 3);
    Wf[idx] = f2bf(W[kk * N + col]);
  } else {
    const int eg = (b - 960) * 256 + threadIdx.x;
    const int r1 = e2f[2 * eg], r2 = e2f[2 * eg + 1];
    if (!(emask[eg] != 0 && r1 >= 0 && r2 >= 0)) return;
    const int bb = eg >> 15;
    const int f1 = r1 > NF - 1 ? NF - 1 : r1;
    const int f2 = r2 > NF - 1 ? NF - 1 : r2;
    const int i1 = bb * NF + f1, i2 = bb * NF + f2;
    const int p1 = atomicAdd(cntI + i1, 1);
    if (p1 < CAP) outInt[(size_t)i1 * DD + p1] = eg;
    const int p2 = atomicAdd(cntI + i2, 1);
    if (p2 < CAP) outInt[(size_t)i2 * DD + p2] = eg;
  }
}

// ---------------- Edge kernel: round-5/7 PROVEN body (64 edges/block, 8 waves,
// 2 blocks/CU). 3-blocks/CU variants (r6/r8/r9) all showed a replay-flaky race
// -> quarantined. Only change vs round 7: gelu_fast/sigmoid_fast (VALU diet).
__global__ __launch_bounds__(512, 4) void k_edge(
    const float* __restrict__ Efeat, const float* __restrict__ Ffeat,
    const int* __restrict__ e2f, const int* __restrict__ emask,
    const unsigned short* __restrict__ W1f, const float* __restrict__ b1,
    const unsigned short* __restrict__ W2f, const float* __restrict__ b2,
    const unsigned short* __restrict__ Wgf, const float* __restrict__ bg,
    const float* __restrict__ ge, const float* __restrict__ be,
    float* __restrict__ out) {
  __shared__ __align__(16) unsigned char pool[69376];
  unsigned short* Xe = (unsigned short*)pool;             // pitch 136
  unsigned short* Xf = (unsigned short*)(pool + 17408);   // pitch 264
  unsigned short* H  = (unsigned short*)(pool + 17408);   // pitch 260
  float*          M  = (float*)(pool + 17408);            // pitch 132
  unsigned short* Mb = (unsigned short*)(pool + 51200);   // pitch 132
  unsigned short* G  = (unsigned short*)(pool + 51200);   // pitch 132
  int*   f1s    = (int*)(pool + 68096);
  int*   f2s    = (int*)(pool + 68352);
  float* validf = (float*)(pool + 68608);
  float* mu     = (float*)(pool + 68864);
  float* rs     = (float*)(pool + 69120);

  const int t = threadIdx.x;
  const int lane = t & 63;
  const int w = t >> 6;   // 0..7
  const int l15 = lane & 15;
  const int l4 = lane >> 4;
  const int eg0 = blockIdx.x * 64;

  if (t < 64) {
    const int eg = eg0 + t;
    const int b = eg >> 15;  // / NE
    const int r1 = e2f[2 * eg], r2 = e2f[2 * eg + 1];
    const bool v = (emask[eg] != 0) && (r1 >= 0) && (r2 >= 0);
    int f1 = r1 < 0 ? 0 : (r1 > NF - 1 ? NF - 1 : r1);
    int f2 = r2 < 0 ? 0 : (r2 > NF - 1 ? NF - 1 : r2);
    f1s[t] = b * NF + f1;
    f2s[t] = b * NF + f2;
    validf[t] = v ? 1.0f : 0.0f;
  }
  __syncthreads();

  // ---- staging: 16B chunks, coalesced global, b128 LDS stores ----
  for (int k = 0; k < 2; ++k) {  // E rows (block-contiguous in global)
    const int c = k * 512 + t, row = c >> 4, j = c & 15;
    const float* s = Efeat + (size_t)(eg0 + row) * DD + j * 8;
    *(bf16x8*)(Xe + row * 136 + j * 8) =
        pack8(*(const float4*)s, *(const float4*)(s + 4));
  }
  for (int k = 0; k < 2; ++k) {  // F1 gathered rows
    const int c = k * 512 + t, row = c >> 4, j = c & 15;
    const float* s1 = Ffeat + (size_t)f1s[row] * DD + j * 8;
    *(bf16x8*)(Xf + row * 264 + j * 8) =
        pack8(*(const float4*)s1, *(const float4*)(s1 + 4));
  }
  for (int k = 0; k < 2; ++k) {  // F2 gathered rows
    const int c = k * 512 + t, row = c >> 4, j = c & 15;
    const float* s2 = Ffeat + (size_t)f2s[row] * DD + j * 8;
    *(bf16x8*)(Xf + row * 264 + 128 + j * 8) =
        pack8(*(const float4*)s2, *(const float4*)(s2 + 4));
  }
  __syncthreads();

  // ---- GEMM1: (64x384)@(384x256), wave w -> cols [32w, 32w+32) ----
  {
    f32x4 acc[4][2] = {};
    for (int ks = 0; ks < 12; ++ks) {
      bf16x8 a[4];
      if (ks < 4) {
        const int kb = ks * 32 + (l4 << 2);
        for (int r = 0; r < 4; ++r) a[r] = ld_ab(Xe + (r * 16 + l15) * 136 + kb);
      } else {
        const int kb = (ks - 4) * 32 + (l4 << 2);
        for (int r = 0; r < 4; ++r) a[r] = ld_ab(Xf + (r * 16 + l15) * 264 + kb);
      }
      for (int n = 0; n < 2; ++n) {
        const int nt = (w << 1) + n;
        bf16x8 bfr = *(const bf16x8*)(W1f + (((nt * 12 + ks) << 6) + lane) * 8);
        for (int r = 0; r < 4; ++r) acc[r][n] = MFMA16(a[r], bfr, acc[r][n]);
      }
    }
    __syncthreads();  // Xf fully read; H may overwrite it
    for (int n = 0; n < 2; ++n) {
      const int col = (w << 5) + (n << 4) + l15;
      const float bias = b1[col];
      for (int r = 0; r < 4; ++r)
        for (int ri = 0; ri < 4; ++ri) {
          const int rw = r * 16 + (l4 << 2) + ri;
          H[rw * 260 + col] = f2bf(gelu_fast(acc[r][n][ri] + bias));
        }
    }
  }
  __syncthreads();

  // ---- GEMM2: (64x256)@(256x128), wave w -> cols [16w, 16w+16) ----
  {
    f32x4 acc2[4] = {};
    for (int ks = 0; ks < 8; ++ks) {
      const int kb = ks * 32 + (l4 << 2);
      bf16x8 a[4];
      for (int r = 0; r < 4; ++r) a[r] = ld_ab(H + (r * 16 + l15) * 260 + kb);
      bf16x8 bfr = *(const bf16x8*)(W2f + (((w * 8 + ks) << 6) + lane) * 8);
      for (int r = 0; r < 4; ++r) acc2[r] = MFMA16(a[r], bfr, acc2[r]);
    }
    __syncthreads();  // H fully read; M may overwrite it
    const int col = (w << 4) + l15;
    const float bias = b2[col];
    for (int r = 0; r < 4; ++r)
      for (int ri = 0; ri < 4; ++ri) {
        const int rw = r * 16 + (l4 << 2) + ri;
        const float mv = (acc2[r][ri] + bias) * validf[rw];
        M[rw * 132 + col] = mv;
        Mb[rw * 132 + col] = f2bf(mv);
      }
  }
  __syncthreads();

  // ---- GEMM3 (gate): [E | msg](64x256)@(256x128), wave w -> cols [16w,16w+16) ----
  {
    f32x4 acc3[4] = {};
    for (int ks = 0; ks < 8; ++ks) {
      bf16x8 a[4];
      if (ks < 4) {
        const int kb = ks * 32 + (l4 << 2);
        for (int r = 0; r < 4; ++r) a[r] = ld_ab(Xe + (r * 16 + l15) * 136 + kb);
      } else {
        const int kb = (ks - 4) * 32 + (l4 << 2);
        for (int r = 0; r < 4; ++r) a[r] = ld_ab(Mb + (r * 16 + l15) * 132 + kb);
      }
      bf16x8 bfr = *(const bf16x8*)(Wgf + (((w * 8 + ks) << 6) + lane) * 8);
      for (int r = 0; r < 4; ++r) acc3[r] = MFMA16(a[r], bfr, acc3[r]);
    }
    __syncthreads();  // Mb fully read; G may overwrite it
    const int col = (w << 4) + l15;
    const float bias = bg[col];
    for (int r = 0; r < 4; ++r)
      for (int ri = 0; ri < 4; ++ri) {
        const int rw = r * 16 + (l4 << 2) + ri;
        G[rw * 132 + col] = f2bf(sigmoid_fast(acc3[r][ri] + bias));
      }
  }
  __syncthreads();

  // ---- u = E + gate*msg (coalesced Efeat read; in place into M) ----
  const int colc = t & 127;
  const int rb = t >> 7;  // wave-uniform, 0..3
  const float gec = ge[colc], bec = be[colc];
  for (int i = 0; i < 16; ++i) {
    const int row = 4 * i + rb;
    const float ev = Efeat[(size_t)(eg0 + row) * DD + colc];
    const float gv = bf2f(G[row * 132 + colc]);
    const float mv = M[row * 132 + colc];
    M[row * 132 + colc] = ev + gv * mv;
  }
  __syncthreads();

  {  // ---- LN stats: 8 threads/row ----
    const int rw = t >> 3, q = t & 7;
    const float* ur = M + rw * 132 + q * 16;
    float s = 0.f, s2 = 0.f;
    for (int j = 0; j < 4; ++j) {
      float4 v = *(const float4*)(ur + 4 * j);
      s += v.x + v.y + v.z + v.w;
      s2 += v.x * v.x + v.y * v.y + v.z * v.z + v.w * v.w;
    }
    s += __shfl_xor(s, 1); s2 += __shfl_xor(s2, 1);
    s += __shfl_xor(s, 2); s2 += __shfl_xor(s2, 2);
    s += __shfl_xor(s, 4); s2 += __shfl_xor(s2, 4);
    if (q == 0) {
      const float mean = s * 0.0078125f;
      const float var = s2 * 0.0078125f - mean * mean;
      mu[rw] = mean;
      rs[rw] = rsqrtf(var + 1e-5f);
    }
  }
  __syncthreads();

  // ---- epilogue: coalesced E_new store ----
  float* eob = out + (size_t)MF * DD;
  for (int i = 0; i < 16; ++i) {
    const int row = 4 * i + rb;  // wave-uniform
    const float o = (M[row * 132 + colc] - mu[row]) * rs[row] * gec + bec;
    eob[(size_t)(eg0 + row) * DD + colc] = o;
  }
}

// ---------------- Face kernel: round-7 proven body (64 faces/block, 8 waves, 3 blocks/CU) ----------------
__global__ __launch_bounds__(512, 6) void k_face(
    const float* __restrict__ Ffeat, const int* __restrict__ fmask,
    const unsigned short* __restrict__ W1f, const float* __restrict__ b1,
    const unsigned short* __restrict__ W2f, const float* __restrict__ b2,
    const unsigned short* __restrict__ Wgf, const float* __restrict__ bg,
    const float* __restrict__ gf, const float* __restrict__ bef,
    float* __restrict__ out, const int* __restrict__ cntI) {
  __shared__ __align__(16) unsigned char pool[51712];
  unsigned short* X  = (unsigned short*)pool;             // pitch 264
  int*          lid  = (int*)(pool + 33792);              // [64][32]
  unsigned short* H  = (unsigned short*)(pool + 33792);   // pitch 136
  unsigned short* Ub = (unsigned short*)(pool + 33792);   // pitch 136
  int*   cnts = (int*)(pool + 51200);
  float* fmv  = (float*)(pool + 51456);

  const int t = threadIdx.x;
  const int lane = t & 63;
  const int w = t >> 6;
  const int l15 = lane & 15;
  const int l4 = lane >> 4;
  const int fg0 = blockIdx.x * 64;
  const int* outInt = (const int*)out;
  const float* Enew = out + (size_t)MF * DD;

  if (t < 64) {
    fmv[t] = fmask[fg0 + t] ? 1.0f : 0.0f;
    cnts[t] = cntI[fg0 + t];
  }
  for (int k = 0; k < 4; ++k) {  // stage id lists
    const int idx = k * 512 + t, row = idx >> 5, p = idx & 31;
    lid[idx] = outInt[(size_t)(fg0 + row) * DD + p];
  }
  for (int k = 0; k < 2; ++k) {  // stage F half of X
    const int c = k * 512 + t, row = c >> 4, j = c & 15;
    const float* sf = Ffeat + (size_t)(fg0 + row) * DD + j * 8;
    *(bf16x8*)(X + row * 264 + j * 8) =
        pack8(*(const float4*)sf, *(const float4*)(sf + 4));
  }
  __syncthreads();

  // ---- gather msg: parallel predicated 8-wide prefetch + rare tail ----
  {
    const int colc = t & 127;
    const int rb = t >> 7;  // 0..3
    for (int i = 0; i < 16; ++i) {
      const int row = 4 * i + rb;
      const int c = cnts[row];
      const int cl = c < CAP ? c : CAP;
      const int* lr = lid + row * 32;
      float s = 0.f;
#pragma unroll
      for (int p = 0; p < 8; ++p) {
        const int idx = (p < cl) ? lr[p] : 0;
        const float v = Enew[(size_t)idx * DD + colc];
        s += (p < cl) ? v : 0.f;
      }
      for (int p = 8; p < cl; ++p) s += Enew[(size_t)lr[p] * DD + colc];
      X[row * 264 + 128 + colc] = f2bf(s / ((float)c + 1e-8f));
    }
  }
  __syncthreads();  // msg complete; lid dead (H may overwrite)

  // ---- GEMM ef1: (64x256)@(256x128) -> GELU -> H, wave w -> cols [16w,16w+16) ----
  {
    f32x4 acc[4] = {};
    for (int ks = 0; ks < 8; ++ks) {
      const int kb = ks * 32 + (l4 << 2);
      bf16x8 a[4];
      for (int r = 0; r < 4; ++r) a[r] = ld_ab(X + (r * 16 + l15) * 264 + kb);
      bf16x8 bfr = *(const bf16x8*)(W1f + (((w * 8 + ks) << 6) + lane) * 8);
      for (int r = 0; r < 4; ++r) acc[r] = MFMA16(a[r], bfr, acc[r]);
    }
    const int col = (w << 4) + l15;
    const float bias = b1[col];
    for (int r = 0; r < 4; ++r)
      for (int ri = 0; ri < 4; ++ri) {
        const int rw = r * 16 + (l4 << 2) + ri;
        H[rw * 136 + col] = f2bf(gelu_fast(acc[r][ri] + bias));
      }
  }
  __syncthreads();

  // ---- GEMM ef2: (64x128)@(128x128) -> Ub bf16 (in place over H) ----
  {
    f32x4 acc2[4] = {};
    for (int ks = 0; ks < 4; ++ks) {
      const int kb = ks * 32 + (l4 << 2);
      bf16x8 a[4];
      for (int r = 0; r < 4; ++r) a[r] = ld_ab(H + (r * 16 + l15) * 136 + kb);
      bf16x8 bfr = *(const bf16x8*)(W2f + (((w * 4 + ks) << 6) + lane) * 8);
      for (int r = 0; r < 4; ++r) acc2[r] = MFMA16(a[r], bfr, acc2[r]);
    }
    __syncthreads();  // H fully read; Ub overwrites same cells
    const int col = (w << 4) + l15;
    const float bias = b2[col];
    for (int r = 0; r < 4; ++r)
      for (int ri = 0; ri < 4; ++ri) {
        const int rw = r * 16 + (l4 << 2) + ri;
        Ub[rw * 136 + col] = f2bf(acc2[r][ri] + bias);
      }
  }
  __syncthreads();

  // ---- GEMM gf: [F | update](64x256)@(256x128); then gate-fold into Ub ----
  {
    f32x4 acc3[4] = {};
    for (int ks = 0; ks < 8; ++ks) {
      bf16x8 a[4];
      if (ks < 4) {
        const int kb = ks * 32 + (l4 << 2);
        for (int r = 0; r < 4; ++r) a[r] = ld_ab(X + (r * 16 + l15) * 264 + kb);
      } else {
        const int kb = (ks - 4) * 32 + (l4 << 2);
        for (int r = 0; r < 4; ++r) a[r] = ld_ab(Ub + (r * 16 + l15) * 136 + kb);
      }
      bf16x8 bfr = *(const bf16x8*)(Wgf + (((w * 8 + ks) << 6) + lane) * 8);
      for (int r = 0; r < 4; ++r) acc3[r] = MFMA16(a[r], bfr, acc3[r]);
    }
    __syncthreads();  // Ub fully read; fold rewrites in place (with face mask)
    const int col = (w << 4) + l15;
    const float bias = bg[col];
    for (int r = 0; r < 4; ++r)
      for (int ri = 0; ri < 4; ++ri) {
        const int rw = r * 16 + (l4 << 2) + ri;
        const int off = rw * 136 + col;
        Ub[off] = f2bf(sigmoid_fast(acc3[r][ri] + bias) * bf2f(Ub[off]) * fmv[rw]);
      }
  }
  __syncthreads();

  // ---- fused u + LN + store F_new (overwrites id-list region of out) ----
  {
    const int rw = t >> 3, q = t & 7;
    const unsigned short* xf = X + rw * 264 + q * 16;
    const unsigned short* ub = Ub + rw * 136 + q * 16;
    bf16x8 e0 = *(const bf16x8*)(xf), e1 = *(const bf16x8*)(xf + 8);
    bf16x8 m0 = *(const bf16x8*)(ub), m1 = *(const bf16x8*)(ub + 8);
    float u[16];
    float s = 0.f, s2 = 0.f;
    for (int jj = 0; jj < 8; ++jj) {
      const float v0 = bf2f((unsigned short)e0[jj]) + bf2f((unsigned short)m0[jj]);
      const float v1 = bf2f((unsigned short)e1[jj]) + bf2f((unsigned short)m1[jj]);
      u[jj] = v0; u[8 + jj] = v1;
      s += v0 + v1; s2 += v0 * v0 + v1 * v1;
    }
    s += __shfl_xor(s, 1); s2 += __shfl_xor(s2, 1);
    s += __shfl_xor(s, 2); s2 += __shfl_xor(s2, 2);
    s += __shfl_xor(s, 4); s2 += __shfl_xor(s2, 4);
    const float mean = s * 0.0078125f;
    const float var = s2 * 0.0078125f - mean * mean;
    const float rstd = rsqrtf(var + 1e-5f);
    float* fo = out + (size_t)(fg0 + rw) * DD + q * 16;
    const float* gfp = gf + q * 16;
    const float* bfp = bef + q * 16;
    for (int c4 = 0; c4 < 4; ++c4) {
      float4 g4 = ((const float4*)gfp)[c4];
      float4 b4 = ((const float4*)bfp)[c4];
      float4 o4;
      o4.x = (u[c4 * 4 + 0] - mean) * rstd * g4.x + b4.x;
      o4.y = (u[c4 * 4 + 1] - mean) * rstd * g4.y + b4.y;
      o4.z = (u[c4 * 4 + 2] - mean) * rstd * g4.z + b4.z;
      o4.w = (u[c4 * 4 + 3] - mean) * rstd * g4.w + b4.w;
      ((float4*)fo)[c4] = o4;
    }
  }
}

extern "C" void kernel_launch(void* const* d_in, const int* in_sizes, int n_in,
                              void* d_out, int out_size, void* d_ws, size_t ws_size,
                              hipStream_t stream) {
  const float* Ffeat = (const float*)d_in[0];
  const float* Efeat = (const float*)d_in[1];
  const int* e2f = (const int*)d_in[2];
  const int* fmask = (const int*)d_in[3];
  const int* emask = (const int*)d_in[4];
  const float* w_fe1 = (const float*)d_in[5];
  const float* b_fe1 = (const float*)d_in[6];
  const float* w_fe2 = (const float*)d_in[7];
  const float* b_fe2 = (const float*)d_in[8];
  const float* w_ge = (const float*)d_in[9];
  const float* b_ge = (const float*)d_in[10];
  const float* g_e = (const float*)d_in[11];
  const float* beta_e = (const float*)d_in[12];
  const float* w_ef1 = (const float*)d_in[13];
  const float* b_ef1 = (const float*)d_in[14];
  const float* w_ef2 = (const float*)d_in[15];
  const float* b_ef2 = (const float*)d_in[16];
  const float* w_gf = (const float*)d_in[17];
  const float* b_gf = (const float*)d_in[18];
  const float* g_f = (const float*)d_in[19];
  const float* beta_f = (const float*)d_in[20];

  float* out = (float*)d_out;
  int* cntI = (int*)d_ws;
  unsigned short* wbase = (unsigned short*)((char*)d_ws + (size_t)MF * sizeof(int));
  unsigned short* W1f = wbase;             // 384*256
  unsigned short* W2f = W1f + 98304;       // 256*128
  unsigned short* Wgf = W2f + 32768;       // 256*128
  unsigned short* Wef1 = Wgf + 32768;      // 256*128
  unsigned short* Wef2 = Wef1 + 32768;     // 128*128
  unsigned short* Wgff = Wef2 + 16384;     // 256*128

  hipMemsetAsync(cntI, 0, (size_t)MF * sizeof(int), stream);

  // one merged prologue launch: 960 pack blocks + 1024 fill blocks
  k_prep<<<1984, 256, 0, stream>>>(w_fe1, w_fe2, w_ge, w_ef1, w_ef2, w_gf,
                                   W1f, W2f, Wgf, Wef1, Wef2, Wgff,
                                   e2f, emask, cntI, (int*)out);

  k_edge<<<ME / 64, 512, 0, stream>>>(Efeat, Ffeat, e2f, emask, W1f, b_fe1, W2f, b_fe2,
                                      Wgf, b_ge, g_e, beta_e, out);
  k_face<<<MF / 64, 512, 0, stream>>>(Ffeat, fmask, Wef1, b_ef1, Wef2, b_ef2,
                                      Wgff, b_gf, g_f, beta_f, out, cntI);
}